// Round 2
// baseline (761.019 us; speedup 1.0000x reference)
//
#include <hip/hip_runtime.h>

// est[bc][f][w] = dot(A[bc][f][:], B[w][:]);  out[bc][8f+i] = est[f][i] + est[f-1][8+i]
// A: [16][16000][512] fp32 (524 MB HBM stream), B: [16][512] (held in VGPRs), out: [16][128008].
//
// One 64-lane wave per 128 output frames, fully autonomous (no LDS, no barriers).
// Lane split: wq = l&7 -> w in {2wq, 2wq+1}; ksl = l>>3 -> k in [ksl*64, ksl*64+64).
// B-regs: 2w x 64k = 128 VGPR/lane.
//
// A is streamed through a 6-slot QUARTER-row register ring (4 x float4 per slot),
// prefetch depth 5 (20 loads / 2.5 KB unique in flight per wave) so issue-to-use
// covers ~900-cycle HBM miss latency. Ring period (6 slots) x 4 quarters/frame
// -> 12-step macro-iteration = 3 frames; 129 frames = 43 macro-iters, so every
// ring index is a compile-time constant (no scratch).
//
// Epilogue per frame: 3x shfl_xor k-reduce (all lanes end with est[f][2wq..2wq+1]),
// then 4 shfl gather of est[f][i] + est[f-1][8+i], 4B store by ksl==0 lanes.

#define FRAMES 16000
#define OUTF   16001               // output sub-blocks per bc (frames 0..16000)
#define OUT_PER_BC 128008          // 8 * OUTF
#define OFPW   128                 // output frames per wave

__global__ __launch_bounds__(64, 2)
void decoder_kernel(const float* __restrict__ A,
                    const float* __restrict__ B,
                    float* __restrict__ out)
{
    const int l   = threadIdx.x & 63;
    const int wq  = l & 7;             // w-pair index
    const int ksl = l >> 3;            // k-slice index
    const int bc  = blockIdx.y;
    const int o0  = blockIdx.x * OFPW;

    // ---- B into registers: Bw[w'][k] = B4[(2wq+w')*128 + ksl*16 + k]
    const float4* B4 = (const float4*)B;
    float4 Bw[2][16];
    #pragma unroll
    for (int w = 0; w < 2; ++w)
        #pragma unroll
        for (int k = 0; k < 16; ++k)
            Bw[w][k] = B4[(2*wq + w) * 128 + ksl*16 + k];

    const float4* Abc = (const float4*)A + (size_t)bc * FRAMES * 128;

    float4 ring[6][4];                 // 6 quarter-row slots, 96 VGPR
    float acc0 = 0.f, acc1 = 0.f;      // per-frame dot accumulators (w', own k-slice)
    float prev0 = 0.f, prev1 = 0.f;    // est[f-1][2wq], est[f-1][2wq+1]

    // SLOT and Q are always literals -> ring/Bw indices constant-fold (no scratch).
#define LOADQ(SLOT, FIDX, Q) do {                                         \
        int fc_ = o0 - 1 + (FIDX);                                        \
        fc_ = fc_ < 0 ? 0 : (fc_ >= FRAMES ? FRAMES - 1 : fc_);           \
        const float4* p_ = Abc + (size_t)fc_ * 128 + ksl * 16 + (Q) * 4;  \
        ring[SLOT][0] = p_[0]; ring[SLOT][1] = p_[1];                     \
        ring[SLOT][2] = p_[2]; ring[SLOT][3] = p_[3];                     \
    } while (0)

#define COMPQ(SLOT, Q) do {                                                   \
        _Pragma("unroll")                                                     \
        for (int j_ = 0; j_ < 4; ++j_) {                                      \
            const float4 a_  = ring[SLOT][j_];                                \
            const float4 b0_ = Bw[0][(Q)*4 + j_];                             \
            const float4 b1_ = Bw[1][(Q)*4 + j_];                             \
            acc0 = fmaf(a_.x, b0_.x, acc0); acc1 = fmaf(a_.x, b1_.x, acc1);   \
            acc0 = fmaf(a_.y, b0_.y, acc0); acc1 = fmaf(a_.y, b1_.y, acc1);   \
            acc0 = fmaf(a_.z, b0_.z, acc0); acc1 = fmaf(a_.z, b1_.z, acc1);   \
            acc0 = fmaf(a_.w, b0_.w, acc0); acc1 = fmaf(a_.w, b1_.w, acc1);   \
        }                                                                     \
    } while (0)

    auto frameEnd = [&](int fidx) {
        float r0 = acc0, r1 = acc1;
        r0 += __shfl_xor(r0, 8);   r1 += __shfl_xor(r1, 8);    // reduce over ksl
        r0 += __shfl_xor(r0, 16);  r1 += __shfl_xor(r1, 16);
        r0 += __shfl_xor(r0, 32);  r1 += __shfl_xor(r1, 32);
        const int f = o0 - 1 + fidx;
        if (f < 0 || f >= FRAMES) { r0 = 0.f; r1 = 0.f; }      // ghost frames
        if (fidx >= 1 && f < OUTF) {                           // wave-uniform branch
            // out[8f+i] = est[f][i] + est[f-1][8+i], one i = wq per lane group
            const int srcA = (l & 56) | (wq >> 1);             // holder of est[f][wq]
            const float xa0 = __shfl(r0, srcA);
            const float xa1 = __shfl(r1, srcA);
            const int srcB = srcA | 4;                         // holder of est[f-1][8+wq]
            const float yb0 = __shfl(prev0, srcB);
            const float yb1 = __shfl(prev1, srcB);
            const float av = (wq & 1) ? xa1 : xa0;
            const float bv = (wq & 1) ? yb1 : yb0;
            if (ksl == 0)
                out[(size_t)bc * OUT_PER_BC + (size_t)f * 8 + wq] = av + bv;
        }
        prev0 = r0; prev1 = r1;
        acc0 = 0.f; acc1 = 0.f;
    };

    // ---- prologue: prime 5 quarter-steps (steps 0..4)
    LOADQ(0, 0, 0); LOADQ(1, 0, 1); LOADQ(2, 0, 2); LOADQ(3, 0, 3);
    LOADQ(4, 1, 0);

    // ---- main loop: 43 macro-iters x 12 quarter-steps = 129 frames (o0-1 .. o0+127)
    // step S: compute slot S%6, quarter S%4, frame fidx=S/4; issue load for step S+5.
    for (int t = 0; t < 43; ++t) {
        const int fb = 3 * t;
        LOADQ(5, fb + 1, 1); COMPQ(0, 0);
        LOADQ(0, fb + 1, 2); COMPQ(1, 1);
        LOADQ(1, fb + 1, 3); COMPQ(2, 2);
        LOADQ(2, fb + 2, 0); COMPQ(3, 3); frameEnd(fb + 0);
        LOADQ(3, fb + 2, 1); COMPQ(4, 0);
        LOADQ(4, fb + 2, 2); COMPQ(5, 1);
        LOADQ(5, fb + 2, 3); COMPQ(0, 2);
        LOADQ(0, fb + 3, 0); COMPQ(1, 3); frameEnd(fb + 1);
        LOADQ(1, fb + 3, 1); COMPQ(2, 0);
        LOADQ(2, fb + 3, 2); COMPQ(3, 1);
        LOADQ(3, fb + 3, 3); COMPQ(4, 2);
        LOADQ(4, fb + 4, 0); COMPQ(5, 3); frameEnd(fb + 2);
    }

#undef LOADQ
#undef COMPQ
}

extern "C" void kernel_launch(void* const* d_in, const int* in_sizes, int n_in,
                              void* d_out, int out_size, void* d_ws, size_t ws_size,
                              hipStream_t stream) {
    const float* A   = (const float*)d_in[0];   // mixture_w
    const float* B   = (const float*)d_in[1];   // basis_weight [16][512]
    float*       out = (float*)d_out;

    // 126 waves per bc, 128 output frames each -> covers 16001 output frames
    dim3 grid(126, 16, 1);
    decoder_kernel<<<grid, dim3(64, 1, 1), 0, stream>>>(A, B, out);
}

// Round 3
// 747.694 us; speedup vs baseline: 1.0178x; 1.0178x over previous
//
#include <hip/hip_runtime.h>

// est[bc][f][w] = dot(A[bc][f][:], B[w][:]);  out[bc][8f+i] = est[f][i] + est[f-1][8+i]
// A: [16][16000][512] fp32 (524 MB HBM stream), B: [16][512] (held in VGPRs), out: [16][128008].
//
// One wave per 128 output frames. Lane split: wq = l&7 -> w in {2wq,2wq+1};
// ksl = l>>3 -> k in [ksl*64, ksl*64+64). B-regs: 2w x 64k = 128 VGPR/lane.
// A loads: lane-contiguous dwordx4, 8 distinct 128B lines per inst, full row
// consumed across the frame's 16 insts (no overfetch). Reduce over ksl: 3 shfl_xor.
//
// NOTE (round-2 post-mortem): a depth-5 quarter-row register ring (issue-to-use
// ~900 cy) was tried and REGRESSED (~94 -> ~111 us decoder component). With
// ~8 waves/CU the depth-1 ping-pong latency is already TLP-hidden; this kernel
// is BW-bound at ~5.7 TB/s (88-90% of the fill-measured 6.4 TB/s achievable).
// Keep the cheap LDS-amortized epilogue and half-row ping-pong.

#define FRAMES 16000
#define EDIM   512
#define OUTF   16001               // output sub-blocks per bc (frames 0..16000)
#define OUT_PER_BC 128008          // 8 * OUTF
#define BATCHES 16
#define OFPW    128                // output frames per wave

__global__ __launch_bounds__(128, 2)
void decoder_kernel(const float* __restrict__ A,
                    const float* __restrict__ B,
                    float* __restrict__ out)
{
    const int t   = threadIdx.x;
    const int wid = t >> 6;            // wave in block
    const int l   = t & 63;
    const int wq  = l & 7;             // w-pair index
    const int ksl = l >> 3;            // k-slice index
    const int bc  = blockIdx.y;
    const int o0  = (blockIdx.x * 2 + wid) * OFPW;

    __shared__ float ring[2][16][16];  // per-wave est ring: [wave][frame&15][w]

    // ---- B into registers: Bw[w'][h][j] = B[2wq+w'][ksl*64 + h*32 + 4j .. +3]
    const float4* B4 = (const float4*)B;
    float4 Bw[2][2][8];
    #pragma unroll
    for (int w = 0; w < 2; ++w)
        #pragma unroll
        for (int h = 0; h < 2; ++h)
            #pragma unroll
            for (int j = 0; j < 8; ++j)
                Bw[w][h][j] = B4[(2*wq + w) * 128 + ksl*16 + h*8 + j];

    const float4* Abc = (const float4*)(A + (size_t)bc * FRAMES * EDIM);
    // frame f, half h, j: float4 index f*128 + ksl*16 + h*8 + j

    float4 Abuf[2][8];                 // half-row ping-pong (1 KB/wave each)

    auto loadHalf = [&](float4* dst, int f, int h) {
        int fc = f; if (fc < 0) fc = 0; if (fc >= FRAMES) fc = FRAMES - 1;
        const float4* p = Abc + (size_t)fc * 128 + ksl*16 + h*8;
        #pragma unroll
        for (int j = 0; j < 8; ++j) dst[j] = p[j];
    };

    // Invariant at processFrame(f) entry: Abuf[0] holds (f, h0).
    // On exit: Abuf[0] holds (f+1, h0).
    auto processFrame = [&](int f) {
        loadHalf(Abuf[1], f, 1);                   // (f, h1) in flight
        float acc[2][2] = {{0.f,0.f},{0.f,0.f}};   // [w'][h] chains
        #pragma unroll
        for (int j = 0; j < 8; ++j) {              // compute h0
            const float4 a = Abuf[0][j];
            acc[0][0] = fmaf(a.x, Bw[0][0][j].x, acc[0][0]);
            acc[0][0] = fmaf(a.y, Bw[0][0][j].y, acc[0][0]);
            acc[0][0] = fmaf(a.z, Bw[0][0][j].z, acc[0][0]);
            acc[0][0] = fmaf(a.w, Bw[0][0][j].w, acc[0][0]);
            acc[1][0] = fmaf(a.x, Bw[1][0][j].x, acc[1][0]);
            acc[1][0] = fmaf(a.y, Bw[1][0][j].y, acc[1][0]);
            acc[1][0] = fmaf(a.z, Bw[1][0][j].z, acc[1][0]);
            acc[1][0] = fmaf(a.w, Bw[1][0][j].w, acc[1][0]);
        }
        loadHalf(Abuf[0], f + 1, 0);               // (f+1, h0) in flight
        #pragma unroll
        for (int j = 0; j < 8; ++j) {              // compute h1
            const float4 a = Abuf[1][j];
            acc[0][1] = fmaf(a.x, Bw[0][1][j].x, acc[0][1]);
            acc[0][1] = fmaf(a.y, Bw[0][1][j].y, acc[0][1]);
            acc[0][1] = fmaf(a.z, Bw[0][1][j].z, acc[0][1]);
            acc[0][1] = fmaf(a.w, Bw[0][1][j].w, acc[0][1]);
            acc[1][1] = fmaf(a.x, Bw[1][1][j].x, acc[1][1]);
            acc[1][1] = fmaf(a.y, Bw[1][1][j].y, acc[1][1]);
            acc[1][1] = fmaf(a.z, Bw[1][1][j].z, acc[1][1]);
            acc[1][1] = fmaf(a.w, Bw[1][1][j].w, acc[1][1]);
        }
        float r0 = acc[0][0] + acc[0][1];
        float r1 = acc[1][0] + acc[1][1];
        r0 += __shfl_xor(r0, 8);   r1 += __shfl_xor(r1, 8);    // reduce over ksl
        r0 += __shfl_xor(r0, 16);  r1 += __shfl_xor(r1, 16);
        r0 += __shfl_xor(r0, 32);  r1 += __shfl_xor(r1, 32);
        if (f < 0 || f >= FRAMES) { r0 = 0.f; r1 = 0.f; }      // ghost frames
        if (ksl == 0) {                                        // 8 lanes write est[f][:]
            *(float2*)&ring[wid][f & 15][2*wq] = make_float2(r0, r1);
        }
    };

    loadHalf(Abuf[0], o0 - 1, 0);
    processFrame(o0 - 1);                          // prologue: est[o0-1] into ring

    for (int b = 0; b < BATCHES; ++b) {
        const int cf = o0 + b * 8;
        #pragma unroll
        for (int r = 0; r < 8; ++r) processFrame(cf + r);
        __syncthreads();                           // ring write->read visibility
        // overlap-add epilogue: 64 contiguous outputs (frames cf..cf+7)
        const int fr = cf + (l >> 3);
        const float v = ring[wid][fr & 15][l & 7]
                      + ring[wid][(fr - 1) & 15][8 + (l & 7)];
        if (fr < OUTF)
            out[(size_t)bc * OUT_PER_BC + (size_t)cf * 8 + l] = v;
    }
}

extern "C" void kernel_launch(void* const* d_in, const int* in_sizes, int n_in,
                              void* d_out, int out_size, void* d_ws, size_t ws_size,
                              hipStream_t stream) {
    const float* A   = (const float*)d_in[0];   // mixture_w
    const float* B   = (const float*)d_in[1];   // basis_weight [16][512]
    float*       out = (float*)d_out;

    // 126 waves per bc (63 blocks x 2 waves), 128 output frames each -> covers 16001
    dim3 grid(63, 16, 1);
    decoder_kernel<<<grid, dim3(128, 1, 1), 0, stream>>>(A, B, out);
}